// Round 3
// baseline (1712.323 us; speedup 1.0000x reference)
//
#include <hip/hip_runtime.h>
#include <hip/hip_bf16.h>

#define GN 16384
#define GD 128
#define KSPLIT 4
#define KBLK (GN / KSPLIT)   // 4096 k per wave
#define STEPS (KBLK / 32)    // 128 mfma k-steps per wave
#define OUT_ELEMS (GN * GD)

typedef __attribute__((ext_vector_type(8))) short short8;
typedef __attribute__((ext_vector_type(4))) float floatx4;
typedef __attribute__((ext_vector_type(4))) int intx4;

static __device__ __forceinline__ unsigned short f32_to_bf16(float f) {
  unsigned u = __builtin_bit_cast(unsigned, f);
  unsigned r = u + 0x7FFFu + ((u >> 16) & 1u);  // RNE (inputs finite/normal)
  return (unsigned short)(r >> 16);
}

// Kernel 1: xT[d][j] <- bf16(x[j][d])  (4 MiB, L2/L3-resident)
__global__ __launch_bounds__(256) void prep_kernel(const float* __restrict__ x,
                                                   unsigned short* __restrict__ xT) {
  __shared__ unsigned short t[GD][66];
  const int tid = threadIdx.x;
  const int j0 = blockIdx.x * 64;
  for (int i = tid; i < 64 * GD; i += 256) {
    int j = i >> 7, d = i & (GD - 1);
    t[d][j] = f32_to_bf16(x[(size_t)(j0 + j) * GD + d]);
  }
  __syncthreads();
  for (int i = tid; i < GD * 32; i += 256) {
    int d = i >> 5, jp = i & 31;
    unsigned lo = t[d][2 * jp], hi = t[d][2 * jp + 1];
    *reinterpret_cast<unsigned*>(xT + (size_t)d * GN + j0 + 2 * jp) = lo | (hi << 16);
  }
}

// Kernel 2 (RESTRUCTURED): barrier-free, LDS-free streaming GEMM.
// Diagnosis: R0's 32-phase barrier-locked LDS pipeline ran at ~10 us per
// phase-slot vs ~0.5 us of actual work, and cutting its HBM stream 32x
// (R1/R2 bitmask) recovered nothing -> the phase/barrier structure, not
// bandwidth, was binding. B (xT, 4 MiB) is L1/L2-resident, so LDS staging
// is pure overhead here. Now each wave independently:
//   - owns a 16-row x 128-col tile, k-slice of 4096 (KSPLIT=4)
//   - streams adj via a 4-step register ring (8 intx4 in flight ~ 800 cyc
//     prefetch depth ~ HBM latency)
//   - reads B frags directly from L1/L2 (all 16 waves/CU share addresses)
//   - zero __syncthreads, zero LDS, no lockstep.
// 1024 blocks x 256 thr, VGPR<=128 -> 16 waves/CU, full residency, no tail.
// Numerics bit-identical to R0 (same A/B values, same k-order).
__global__ __launch_bounds__(256, 4) void gemm_kernel(const int* __restrict__ adj,
                                                      const unsigned short* __restrict__ xT,
                                                      float* __restrict__ partials) {
  const int tid = threadIdx.x;
  const int wave = tid >> 6;
  const int lane = tid & 63;
  const int q = lane >> 4;   // 0..3
  const int m = lane & 15;   // 0..15
  const int tile = blockIdx.x * 4 + wave;  // 0..1023
  const int rbase = tile * 16;
  const int ks = blockIdx.y;
  const int kbase = ks * KBLK;

  // adj: lane reads row rbase+m, ints [step*32 + q*8, +8) of its k-slice
  const int* arow = adj + (size_t)(rbase + m) * GN + kbase + q * 8;
  // B: frag cc needs xT[n=cc*16+m][kbase + step*32 + q*8 .. +8)
  const unsigned short* brow = xT + (size_t)m * GN + kbase + q * 8;

  floatx4 acc[8];
#pragma unroll
  for (int c = 0; c < 8; ++c) acc[c] = (floatx4){0.f, 0.f, 0.f, 0.f};

  // 4-step adj prefetch ring (2 intx4 per step)
  intx4 ra[4], rb[4];
#pragma unroll
  for (int j = 0; j < 4; ++j) {
    ra[j] = *(const intx4*)(arow + j * 32);
    rb[j] = *(const intx4*)(arow + j * 32 + 4);
  }

  for (int ch = 0; ch < STEPS; ch += 4) {
#pragma unroll
    for (int j = 0; j < 4; ++j) {
      const int s = ch + j;
      const intx4 r0 = ra[j], r1 = rb[j];
      // reload ring slot for step s+4 (mask wraps the tail; wrapped loads are
      // L2-warm and their values are never consumed)
      const int sn = (s + 4) & (STEPS - 1);
      ra[j] = *(const intx4*)(arow + sn * 32);
      rb[j] = *(const intx4*)(arow + sn * 32 + 4);

      // A frag: identical packing to R0 (0/1 int -> bf16 0x0000/0x3F80)
      intx4 pk;
      pk.x = (r0.x | (r0.y << 16)) * 0x3F80;
      pk.y = (r0.z | (r0.w << 16)) * 0x3F80;
      pk.z = (r1.x | (r1.y << 16)) * 0x3F80;
      pk.w = (r1.z | (r1.w << 16)) * 0x3F80;
      const short8 af = __builtin_bit_cast(short8, pk);

      // B frags straight from L1/L2 (no LDS)
      short8 bf[8];
#pragma unroll
      for (int cc = 0; cc < 8; ++cc)
        bf[cc] = *(const short8*)(brow + (size_t)cc * (16 * GN) + s * 32);

#pragma unroll
      for (int cc = 0; cc < 8; ++cc)
        acc[cc] = __builtin_amdgcn_mfma_f32_16x16x32_bf16(af, bf[cc], acc[cc], 0, 0, 0);
    }
  }

  // Epilogue: C/D frag col=lane&15 (=m), row=q*4+r.
  float* pp = partials + (size_t)ks * OUT_ELEMS + (size_t)rbase * GD;
#pragma unroll
  for (int cc = 0; cc < 8; ++cc)
#pragma unroll
    for (int r = 0; r < 4; ++r)
      pp[(size_t)(q * 4 + r) * GD + cc * 16 + m] = acc[cc][r];
}

// Kernel 3: out = x + sum of 4 partials (also un-poisons d_out)
__global__ __launch_bounds__(256) void reduce_kernel(const float* __restrict__ x,
                                                     const float* __restrict__ partials,
                                                     float* __restrict__ out) {
  size_t i = ((size_t)blockIdx.x * 256 + threadIdx.x) * 4;
  floatx4 v = *(const floatx4*)(x + i);
  v += *(const floatx4*)(partials + 0 * (size_t)OUT_ELEMS + i);
  v += *(const floatx4*)(partials + 1 * (size_t)OUT_ELEMS + i);
  v += *(const floatx4*)(partials + 2 * (size_t)OUT_ELEMS + i);
  v += *(const floatx4*)(partials + 3 * (size_t)OUT_ELEMS + i);
  *(floatx4*)(out + i) = v;
}

extern "C" void kernel_launch(void* const* d_in, const int* in_sizes, int n_in,
                              void* d_out, int out_size, void* d_ws, size_t ws_size,
                              hipStream_t stream) {
  const float* x = (const float*)d_in[0];
  const int* adj = (const int*)d_in[1];
  float* out = (float*)d_out;
  unsigned short* xT = (unsigned short*)d_ws;                     // 4 MiB
  float* partials = (float*)((char*)d_ws + (size_t)GN * GD * 2);  // 4 x 8 MiB

  prep_kernel<<<GN / 64, 256, 0, stream>>>(x, xT);
  gemm_kernel<<<dim3(GN / 64, KSPLIT), 256, 0, stream>>>(adj, xT, partials);
  reduce_kernel<<<OUT_ELEMS / 4 / 256, 256, 0, stream>>>(x, partials, out);
}

// Round 5
// 1524.625 us; speedup vs baseline: 1.1231x; 1.1231x over previous
//
#include <hip/hip_runtime.h>
#include <hip/hip_bf16.h>

#define GN 16384
#define GD 128
#define KSPLIT 4
#define KBLK (GN / KSPLIT)        // 4096 k per block
#define PHK 128                   // k per LDS phase
#define NPH (KBLK / PHK)          // 32 phases
#define NSTEP (PHK / 32)          // 4 mfma k-steps per phase
#define BUF_SHORTS (GD * PHK)     // 16384 shorts = 32 KB per buffer
#define OUT_ELEMS (GN * GD)
#define REPS 2                    // DIAGNOSTIC: run gemm phase-loop twice so the
                                  // dispatch exceeds the ~685us poison fills and
                                  // surfaces in rocprof top-5 with full counters.
                                  // total-700 = 2x gemm -> exact attribution.

typedef __attribute__((ext_vector_type(8))) short short8;
typedef __attribute__((ext_vector_type(4))) float floatx4;
typedef __attribute__((ext_vector_type(4))) int intx4;

static __device__ __forceinline__ unsigned short f32_to_bf16(float f) {
  unsigned u = __builtin_bit_cast(unsigned, f);
  unsigned r = u + 0x7FFFu + ((u >> 16) & 1u);  // RNE (inputs finite/normal)
  return (unsigned short)(r >> 16);
}

// Kernel 1: xT[d][j] <- bf16(x[j][d])  (4 MiB, L2/L3-resident)
__global__ __launch_bounds__(256) void prep_kernel(const float* __restrict__ x,
                                                   unsigned short* __restrict__ xT) {
  __shared__ unsigned short t[GD][66];
  const int tid = threadIdx.x;
  const int j0 = blockIdx.x * 64;
  for (int i = tid; i < 64 * GD; i += 256) {
    int j = i >> 7, d = i & (GD - 1);
    t[d][j] = f32_to_bf16(x[(size_t)(j0 + j) * GD + d]);
  }
  __syncthreads();
  for (int i = tid; i < GD * 32; i += 256) {
    int d = i >> 5, jp = i & 31;
    unsigned lo = t[d][2 * jp], hi = t[d][2 * jp + 1];
    *reinterpret_cast<unsigned*>(xT + (size_t)d * GN + j0 + 2 * jp) = lo | (hi << 16);
  }
}

// Kernel 2: EXACT R0 structure (best measured) + PHASE-OFFSET STAGGER.
// Theory under test: R0's blocks are phase-synchronized, so at any instant the
// whole chip reads the same 512-B column window of 64-KB-stride adj rows ->
// only ~4 active column positions chip-wide -> HBM channel starvation ->
// effective adj BW ~1.7 TB/s (645us instead of ~200us). Stagger: block b
// starts its phase ring at ph0 = b&31, so all 32 column windows x 4 ksplits
// are active simultaneously -> full channel spread. Same data, same per-phase
// work; only the k-accumulation ORDER rotates (fp reorder noise << bf16-level
// absmax 2.0). REPS=2 wraps the whole loop for observability (see above).
__global__ __launch_bounds__(512, 4) void gemm_kernel(const int* __restrict__ adj,
                                                      const unsigned short* __restrict__ xT,
                                                      float* __restrict__ partials) {
  __shared__ unsigned short bbuf[2][BUF_SHORTS];  // 2 x 32 KB
  const int tid = threadIdx.x;
  const int wave = tid >> 6;
  const int lane = tid & 63;
  const int q = lane >> 4;   // 0..3
  const int m = lane & 15;   // 0..15
  const int rbase = blockIdx.x * 128 + wave * 16;
  const int ks = blockIdx.y;
  const int kbase = ks * KBLK;
  const int ph0 = blockIdx.x & (NPH - 1);  // stagger offset, 0..31

  // staging: 4 granules (16 B) per thread; slot s = tid + 512p; row n = s>>4
  const unsigned short* gptr[4];
  unsigned short* lptr[4];
#pragma unroll
  for (int p = 0; p < 4; ++p) {
    int s = tid + 512 * p;            // 0..2047
    int n = s >> 4;                   // B row (= d) 0..127
    int gsrc = (s & 15) ^ (n & 7);    // XOR swizzle (involution on low 3 bits)
    gptr[p] = xT + (size_t)n * GN + kbase + gsrc * 8;
    lptr[p] = &bbuf[0][0] + (size_t)s * 8;
  }

#define STAGE(bufsel, koff)                                                             \
  do {                                                                                  \
    _Pragma("unroll") for (int p = 0; p < 4; ++p) {                                     \
      __builtin_amdgcn_global_load_lds(                                                 \
          (const __attribute__((address_space(1))) unsigned int*)(gptr[p] + (koff)),    \
          (__attribute__((address_space(3))) unsigned int*)(lptr[p] +                   \
                                                           (bufsel) * BUF_SHORTS),      \
          16, 0, 0);                                                                    \
    }                                                                                   \
  } while (0)

  const int* a0 = adj + (size_t)(rbase + m) * GN + kbase + q * 8;

  floatx4 acc[8];

  for (int rep = 0; rep < REPS; ++rep) {
#pragma unroll
    for (int c = 0; c < 8; ++c) acc[c] = (floatx4){0.f, 0.f, 0.f, 0.f};

    // preload phase ph0: staging + all 8 adj frag-loads
    const int phr0 = ph0;  // PHR(0)
    STAGE(0, phr0 * PHK);
    intx4 cadj[8];
    {
      const int* ac = a0 + phr0 * PHK;
#pragma unroll
      for (int u = 0; u < 8; ++u)
        cadj[u] = *(const intx4*)(ac + (u >> 1) * 32 + (u & 1) * 4);
    }

    int buf = 0;
    for (int ph = 0; ph < NPH; ++ph) {
      __syncthreads();  // staged buf complete (vmcnt(0) drained here)
      intx4 nadj[8];
      if (ph + 1 < NPH) {
        const int phrn = (ph0 + ph + 1) & (NPH - 1);
        STAGE(buf ^ 1, phrn * PHK);
        const int* an = a0 + phrn * PHK;
#pragma unroll
        for (int u = 0; u < 8; ++u)
          nadj[u] = *(const intx4*)(an + (u >> 1) * 32 + (u & 1) * 4);
      }

#pragma unroll
      for (int st = 0; st < NSTEP; ++st) {
        // B frags: lane(q,m), col-tile cc -> row n=cc*16+m, granule (st*4+q)^(m&7)
        short8 bf[8];
        const unsigned short* bb = &bbuf[buf][0] + (((st * 4 + q) ^ (m & 7)) * 8);
#pragma unroll
        for (int cc = 0; cc < 8; ++cc)
          bf[cc] = *(const short8*)(bb + (cc * 16 + m) * PHK);

        // adj 0/1 int -> bf16 0x0000/0x3F80 (two elems per dword)
        const intx4 r0 = cadj[2 * st], r1 = cadj[2 * st + 1];
        intx4 pk;
        pk.x = (r0.x | (r0.y << 16)) * 0x3F80;
        pk.y = (r0.z | (r0.w << 16)) * 0x3F80;
        pk.z = (r1.x | (r1.y << 16)) * 0x3F80;
        pk.w = (r1.z | (r1.w << 16)) * 0x3F80;
        const short8 af = __builtin_bit_cast(short8, pk);

#pragma unroll
        for (int cc = 0; cc < 8; ++cc)
          acc[cc] = __builtin_amdgcn_mfma_f32_16x16x32_bf16(af, bf[cc], acc[cc], 0, 0, 0);
      }

#pragma unroll
      for (int u = 0; u < 8; ++u) cadj[u] = nadj[u];
      buf ^= 1;
    }
    // rep boundary: buf is back to 0 (NPH even); buf0's last readers finished
    // before the ph=NPH-1 barrier, so next rep's STAGE(0,...) is race-free.
  }

  // Epilogue: plain stores. C/D: col=lane&15, row=q*4+reg.
  float* pp = partials + (size_t)ks * OUT_ELEMS + (size_t)rbase * GD;
#pragma unroll
  for (int cc = 0; cc < 8; ++cc)
#pragma unroll
    for (int r = 0; r < 4; ++r)
      pp[(size_t)(q * 4 + r) * GD + cc * 16 + m] = acc[cc][r];
}

// Kernel 3: out = x + sum of 4 partials (also un-poisons d_out)
__global__ __launch_bounds__(256) void reduce_kernel(const float* __restrict__ x,
                                                     const float* __restrict__ partials,
                                                     float* __restrict__ out) {
  size_t i = ((size_t)blockIdx.x * 256 + threadIdx.x) * 4;
  floatx4 v = *(const floatx4*)(x + i);
  v += *(const floatx4*)(partials + 0 * (size_t)OUT_ELEMS + i);
  v += *(const floatx4*)(partials + 1 * (size_t)OUT_ELEMS + i);
  v += *(const floatx4*)(partials + 2 * (size_t)OUT_ELEMS + i);
  v += *(const floatx4*)(partials + 3 * (size_t)OUT_ELEMS + i);
  *(floatx4*)(out + i) = v;
}

extern "C" void kernel_launch(void* const* d_in, const int* in_sizes, int n_in,
                              void* d_out, int out_size, void* d_ws, size_t ws_size,
                              hipStream_t stream) {
  const float* x = (const float*)d_in[0];
  const int* adj = (const int*)d_in[1];
  float* out = (float*)d_out;
  unsigned short* xT = (unsigned short*)d_ws;                     // 4 MiB
  float* partials = (float*)((char*)d_ws + (size_t)GN * GD * 2);  // 4 x 8 MiB

  prep_kernel<<<GN / 64, 256, 0, stream>>>(x, xT);
  gemm_kernel<<<dim3(GN / 128, KSPLIT), 512, 0, stream>>>(adj, xT, partials);
  reduce_kernel<<<OUT_ELEMS / 4 / 256, 256, 0, stream>>>(x, partials, out);
}

// Round 6
// 1352.906 us; speedup vs baseline: 1.2657x; 1.1269x over previous
//
#include <hip/hip_runtime.h>
#include <hip/hip_bf16.h>

#define GN 16384
#define GD 128
#define KSPLIT 4
#define KBLK (GN / KSPLIT)        // 4096 k per block
#define PHK 128                   // k per LDS phase
#define NPH (KBLK / PHK)          // 32 phases
#define NSTEP (PHK / 32)          // 4 mfma k-steps per phase
#define BUF_SHORTS (GD * PHK)     // 16384 shorts = 32 KB per buffer
#define OUT_ELEMS (GN * GD)

typedef __attribute__((ext_vector_type(8))) short short8;
typedef __attribute__((ext_vector_type(4))) float floatx4;
typedef __attribute__((ext_vector_type(4))) int intx4;

static __device__ __forceinline__ unsigned short f32_to_bf16(float f) {
  unsigned u = __builtin_bit_cast(unsigned, f);
  unsigned r = u + 0x7FFFu + ((u >> 16) & 1u);  // RNE (inputs finite/normal)
  return (unsigned short)(r >> 16);
}

// Kernel 1: xT[d][j] <- bf16(x[j][d])  (4 MiB, L2/L3-resident)
__global__ __launch_bounds__(256) void prep_kernel(const float* __restrict__ x,
                                                   unsigned short* __restrict__ xT) {
  __shared__ unsigned short t[GD][66];
  const int tid = threadIdx.x;
  const int j0 = blockIdx.x * 64;
  for (int i = tid; i < 64 * GD; i += 256) {
    int j = i >> 7, d = i & (GD - 1);
    t[d][j] = f32_to_bf16(x[(size_t)(j0 + j) * GD + d]);
  }
  __syncthreads();
  for (int i = tid; i < GD * 32; i += 256) {
    int d = i >> 5, jp = i & 31;
    unsigned lo = t[d][2 * jp], hi = t[d][2 * jp + 1];
    *reinterpret_cast<unsigned*>(xT + (size_t)d * GN + j0 + 2 * jp) = lo | (hi << 16);
  }
}

// Kernel 2: R0 structure + PHASE-OFFSET STAGGER (confirmed R5: gemm 640 -> ~407
// us/rep, -37%). Mechanism: without stagger all blocks read the same 512-B
// column window of 64-KB-stride adj rows simultaneously -> HBM channel
// starvation. Block b starts its phase ring at ph0 = b&31 so all 32 column
// windows are in flight chip-wide. REPS diagnostic removed (pure-win config;
// attribution stays by subtraction since gemm ~405us < fill ~685us).
__global__ __launch_bounds__(512, 4) void gemm_kernel(const int* __restrict__ adj,
                                                      const unsigned short* __restrict__ xT,
                                                      float* __restrict__ partials) {
  __shared__ unsigned short bbuf[2][BUF_SHORTS];  // 2 x 32 KB
  const int tid = threadIdx.x;
  const int wave = tid >> 6;
  const int lane = tid & 63;
  const int q = lane >> 4;   // 0..3
  const int m = lane & 15;   // 0..15
  const int rbase = blockIdx.x * 128 + wave * 16;
  const int ks = blockIdx.y;
  const int kbase = ks * KBLK;
  const int ph0 = blockIdx.x & (NPH - 1);  // stagger offset, 0..31 (as measured R5)

  // staging: 4 granules (16 B) per thread; slot s = tid + 512p; row n = s>>4
  const unsigned short* gptr[4];
  unsigned short* lptr[4];
#pragma unroll
  for (int p = 0; p < 4; ++p) {
    int s = tid + 512 * p;            // 0..2047
    int n = s >> 4;                   // B row (= d) 0..127
    int gsrc = (s & 15) ^ (n & 7);    // XOR swizzle (involution on low 3 bits)
    gptr[p] = xT + (size_t)n * GN + kbase + gsrc * 8;
    lptr[p] = &bbuf[0][0] + (size_t)s * 8;
  }

#define STAGE(bufsel, koff)                                                             \
  do {                                                                                  \
    _Pragma("unroll") for (int p = 0; p < 4; ++p) {                                     \
      __builtin_amdgcn_global_load_lds(                                                 \
          (const __attribute__((address_space(1))) unsigned int*)(gptr[p] + (koff)),    \
          (__attribute__((address_space(3))) unsigned int*)(lptr[p] +                   \
                                                           (bufsel) * BUF_SHORTS),      \
          16, 0, 0);                                                                    \
    }                                                                                   \
  } while (0)

  const int* a0 = adj + (size_t)(rbase + m) * GN + kbase + q * 8;

  floatx4 acc[8];
#pragma unroll
  for (int c = 0; c < 8; ++c) acc[c] = (floatx4){0.f, 0.f, 0.f, 0.f};

  // preload phase ph0: staging + all 8 adj frag-loads
  STAGE(0, ph0 * PHK);
  intx4 cadj[8];
  {
    const int* ac = a0 + ph0 * PHK;
#pragma unroll
    for (int u = 0; u < 8; ++u)
      cadj[u] = *(const intx4*)(ac + (u >> 1) * 32 + (u & 1) * 4);
  }

  int buf = 0;
  for (int ph = 0; ph < NPH; ++ph) {
    __syncthreads();  // staged buf complete (vmcnt(0) drained here)
    intx4 nadj[8];
    if (ph + 1 < NPH) {
      const int phrn = (ph0 + ph + 1) & (NPH - 1);
      STAGE(buf ^ 1, phrn * PHK);
      const int* an = a0 + phrn * PHK;
#pragma unroll
      for (int u = 0; u < 8; ++u)
        nadj[u] = *(const intx4*)(an + (u >> 1) * 32 + (u & 1) * 4);
    }

#pragma unroll
    for (int st = 0; st < NSTEP; ++st) {
      // B frags: lane(q,m), col-tile cc -> row n=cc*16+m, granule (st*4+q)^(m&7)
      short8 bf[8];
      const unsigned short* bb = &bbuf[buf][0] + (((st * 4 + q) ^ (m & 7)) * 8);
#pragma unroll
      for (int cc = 0; cc < 8; ++cc)
        bf[cc] = *(const short8*)(bb + (cc * 16 + m) * PHK);

      // adj 0/1 int -> bf16 0x0000/0x3F80 (two elems per dword)
      const intx4 r0 = cadj[2 * st], r1 = cadj[2 * st + 1];
      intx4 pk;
      pk.x = (r0.x | (r0.y << 16)) * 0x3F80;
      pk.y = (r0.z | (r0.w << 16)) * 0x3F80;
      pk.z = (r1.x | (r1.y << 16)) * 0x3F80;
      pk.w = (r1.z | (r1.w << 16)) * 0x3F80;
      const short8 af = __builtin_bit_cast(short8, pk);

#pragma unroll
      for (int cc = 0; cc < 8; ++cc)
        acc[cc] = __builtin_amdgcn_mfma_f32_16x16x32_bf16(af, bf[cc], acc[cc], 0, 0, 0);
    }

#pragma unroll
    for (int u = 0; u < 8; ++u) cadj[u] = nadj[u];
    buf ^= 1;
  }

  // Epilogue: plain stores. C/D: col=lane&15, row=q*4+reg.
  float* pp = partials + (size_t)ks * OUT_ELEMS + (size_t)rbase * GD;
#pragma unroll
  for (int cc = 0; cc < 8; ++cc)
#pragma unroll
    for (int r = 0; r < 4; ++r)
      pp[(size_t)(q * 4 + r) * GD + cc * 16 + m] = acc[cc][r];
}

// Kernel 3: out = x + sum of 4 partials (also un-poisons d_out)
__global__ __launch_bounds__(256) void reduce_kernel(const float* __restrict__ x,
                                                     const float* __restrict__ partials,
                                                     float* __restrict__ out) {
  size_t i = ((size_t)blockIdx.x * 256 + threadIdx.x) * 4;
  floatx4 v = *(const floatx4*)(x + i);
  v += *(const floatx4*)(partials + 0 * (size_t)OUT_ELEMS + i);
  v += *(const floatx4*)(partials + 1 * (size_t)OUT_ELEMS + i);
  v += *(const floatx4*)(partials + 2 * (size_t)OUT_ELEMS + i);
  v += *(const floatx4*)(partials + 3 * (size_t)OUT_ELEMS + i);
  *(floatx4*)(out + i) = v;
}

extern "C" void kernel_launch(void* const* d_in, const int* in_sizes, int n_in,
                              void* d_out, int out_size, void* d_ws, size_t ws_size,
                              hipStream_t stream) {
  const float* x = (const float*)d_in[0];
  const int* adj = (const int*)d_in[1];
  float* out = (float*)d_out;
  unsigned short* xT = (unsigned short*)d_ws;                     // 4 MiB
  float* partials = (float*)((char*)d_ws + (size_t)GN * GD * 2);  // 4 x 8 MiB

  prep_kernel<<<GN / 64, 256, 0, stream>>>(x, xT);
  gemm_kernel<<<dim3(GN / 128, KSPLIT), 512, 0, stream>>>(adj, xT, partials);
  reduce_kernel<<<OUT_ELEMS / 4 / 256, 256, 0, stream>>>(x, partials, out);
}